// Round 7
// baseline (328.818 us; speedup 1.0000x reference)
//
#include <hip/hip_runtime.h>
#include <hip/hip_bf16.h>

typedef unsigned short u16;
typedef unsigned int u32;
typedef __attribute__((ext_vector_type(4))) float f32x4;
typedef __attribute__((ext_vector_type(8))) short s16x8;
typedef __attribute__((ext_vector_type(8))) unsigned short u16x8;

#define EPS_V (1e-10f)
#define T_TILES 8

__device__ __forceinline__ u16 f2bf(float f) {   // RNE
  unsigned u = __float_as_uint(f);
  u += 0x7fffu + ((u >> 16) & 1u);
  return (u16)(u >> 16);
}
__device__ __forceinline__ float bf2f(u16 h) {
  return __uint_as_float(((unsigned)h) << 16);
}
__device__ __forceinline__ float wred_sum(float v) {
#pragma unroll
  for (int o = 32; o; o >>= 1) v += __shfl_xor(v, o);
  return v;
}
__device__ __forceinline__ float red16(float v) {  // sum across 16-lane group
  v += __shfl_xor(v, 1); v += __shfl_xor(v, 2);
  v += __shfl_xor(v, 4); v += __shfl_xor(v, 8);
  return v;
}
__device__ __forceinline__ bool mask_at(const void* m, int kind, int idx) {
  if (kind == 0) return ((const int*)m)[idx] != 0;
  if (kind == 1) return ((const float*)m)[idx] != 0.0f;
  return ((const unsigned char*)m)[idx] != 0;
}
// 8 f32 -> 8 bf16 (truncating) via v_perm
__device__ __forceinline__ s16x8 frag_from_f32(f32x4 lo, f32x4 hi) {
  union { s16x8 v; u32 u[4]; } r;
  r.u[0] = __builtin_amdgcn_perm(__float_as_uint(lo[1]), __float_as_uint(lo[0]), 0x07060302u);
  r.u[1] = __builtin_amdgcn_perm(__float_as_uint(lo[3]), __float_as_uint(lo[2]), 0x07060302u);
  r.u[2] = __builtin_amdgcn_perm(__float_as_uint(hi[1]), __float_as_uint(hi[0]), 0x07060302u);
  r.u[3] = __builtin_amdgcn_perm(__float_as_uint(hi[3]), __float_as_uint(hi[2]), 0x07060302u);
  return r.v;
}

// ---------- K0: b0=mask-detect, b1..192=pack 3 chunks, rest=zero accumulators ----------
__global__ __launch_bounds__(256) void k0_fused(
    const unsigned int* __restrict__ mask_raw,
    const float* __restrict__ W_agn, const float* __restrict__ W_nga,
    const float* __restrict__ W_qna,
    int* __restrict__ mkind, u16* __restrict__ Wpack,
    float* __restrict__ zero_base, int nzero, int ndw) {
  const int b = blockIdx.x;
  const int t = threadIdx.x;
  if (b == 0) {
    __shared__ int notInt, notFloat;
    if (t == 0) { notInt = 0; notFloat = 0; }
    __syncthreads();
    int li = 0, lf = 0;
    for (int i = t; i < ndw; i += 256) {
      unsigned v = mask_raw[i];
      if (v != 0u && v != 1u) li = 1;
      if (v != 0u && v != 0x3F800000u) lf = 1;
    }
    if (li) atomicOr(&notInt, 1);
    if (lf) atomicOr(&notFloat, 1);
    __syncthreads();
    if (t == 0) mkind[0] = (!notInt) ? 0 : ((!notFloat) ? 1 : 2);
  } else if (b <= 192) {
    int idx = (b - 1) * 256 + t;   // < 192*256
    int col = idx >> 8, k = idx & 255;
    float v;
    if (col < 64) v = W_agn[col * 256 + k];
    else if (col < 128) v = W_nga[(col - 64) * 256 + k];
    else v = W_qna[(col - 128) * 256 + k];
    Wpack[idx] = f2bf(v);
  } else {
    int idx = (b - 193) * 256 + t;
    if (idx < nzero) zero_base[idx] = 0.f;
  }
}

// ---------- K1: fused GEMM + segment reductions.
// 256 persistent blocks x 512 threads (8 waves), 8 tiles of 64 rows each.
// LDS ring 2x64KB f32 (global_load_lds, counted vmcnt, raw s_barrier).
// Waves 0-5: chunk (agn/nga/qna) x row-half, B in regs (32 frags).
// Wave 6: node logits; wave 7: vsum (values column segsum).
// Outputs: nga_bf store; atomics pa_un,S,V,I,Sn,vsum. ----------
__global__ __launch_bounds__(512, 2) void k1_fused(
    const float* __restrict__ values, const u16* __restrict__ Wpack,
    const int* __restrict__ indices, const void* __restrict__ mask,
    const int* __restrict__ mkind,
    const float* __restrict__ b_agn, const float* __restrict__ b_nga,
    const float* __restrict__ b_qna, const float* __restrict__ w_node,
    u16* __restrict__ nga_bf,
    float* __restrict__ pa_un, float* __restrict__ S_at,
    float* __restrict__ V_at, float* __restrict__ I_at,
    float* __restrict__ Sn_at, float* __restrict__ vsum) {
  __shared__ float ring[2][64 * 256];   // 128 KB
  __shared__ float nl_e[64];
  __shared__ float e_lds[64][65];       // padded stride

  const int t = threadIdx.x;
  const int lane = t & 63;
  const int wave = t >> 6;
  const int ln15 = lane & 15;
  const int kg = lane >> 4;
  const int blk_row0 = blockIdx.x * (T_TILES * 64);

  const int ch = wave >> 1;        // 0 agn, 1 nga, 2 qna, 3 aux
  const int hf = wave & 1;
  const bool is_mfma = (ch < 3);

  // B fragments in registers, loaded once
  s16x8 bfr[4][8];
  float bias_c[4];
  if (is_mfma) {
    const u16* wb = Wpack + (size_t)(ch * 64 + ln15) * 256 + kg * 8;
#pragma unroll
    for (int cg = 0; cg < 4; ++cg)
#pragma unroll
      for (int s = 0; s < 8; ++s)
        bfr[cg][s] = *reinterpret_cast<const s16x8*>(wb + (size_t)(cg * 16) * 256 + s * 32);
    const float* bp = (ch == 0) ? b_agn : (ch == 1) ? b_nga : b_qna;
#pragma unroll
    for (int cg = 0; cg < 4; ++cg) bias_c[cg] = bp[cg * 16 + ln15];
  }
  const int kind = mkind[0];

  // stage tile 0 (wave stages rows wave*8 .. +7; source granule-swizzled)
#pragma unroll
  for (int i = 0; i < 8; ++i) {
    int m = wave * 8 + i;
    const float* gp = values + (size_t)(blk_row0 + m) * 256 + ((lane ^ (m & 7)) << 2);
    __builtin_amdgcn_global_load_lds((const __attribute__((address_space(1))) void*)gp,
        (__attribute__((address_space(3))) void*)&ring[0][m * 256], 16, 0, 0);
  }

  for (int tt = 0; tt < T_TILES; ++tt) {
    const int row0 = blk_row0 + tt * 64;
    const float* buf = ring[tt & 1];

    if (tt + 1 < T_TILES) {
      float* nbuf = ring[(tt + 1) & 1];
#pragma unroll
      for (int i = 0; i < 8; ++i) {
        int m = wave * 8 + i;
        const float* gp = values + (size_t)(row0 + 64 + m) * 256 + ((lane ^ (m & 7)) << 2);
        __builtin_amdgcn_global_load_lds((const __attribute__((address_space(1))) void*)gp,
            (__attribute__((address_space(3))) void*)&nbuf[m * 256], 16, 0, 0);
      }
      asm volatile("s_waitcnt vmcnt(8)" ::: "memory");
    } else {
      asm volatile("s_waitcnt vmcnt(0)" ::: "memory");
    }
    __builtin_amdgcn_sched_barrier(0);
    __builtin_amdgcn_s_barrier();          // ring[tt] ready
    __builtin_amdgcn_sched_barrier(0);

    f32x4 acc[2][4];
    const int rbase = hf * 32;
    const int swz = ln15 & 7;

    if (is_mfma) {
#pragma unroll
      for (int rg = 0; rg < 2; ++rg)
#pragma unroll
        for (int cg = 0; cg < 4; ++cg) acc[rg][cg] = (f32x4){0.f, 0.f, 0.f, 0.f};
#pragma unroll
      for (int s = 0; s < 8; ++s) {
        int gl = s * 8 + kg * 2;    // even logical 16B-granule
        s16x8 afr[2];
#pragma unroll
        for (int rg = 0; rg < 2; ++rg) {
          const float* rp = &buf[(rbase + rg * 16 + ln15) * 256];
          f32x4 lo = *reinterpret_cast<const f32x4*>(rp + ((gl ^ swz) << 2));
          f32x4 hi = *reinterpret_cast<const f32x4*>(rp + (((gl + 1) ^ swz) << 2));
          afr[rg] = frag_from_f32(lo, hi);
        }
#pragma unroll
        for (int cg = 0; cg < 4; ++cg) {
          acc[0][cg] = __builtin_amdgcn_mfma_f32_16x16x32_bf16(afr[0], bfr[cg][s], acc[0][cg], 0, 0, 0);
          acc[1][cg] = __builtin_amdgcn_mfma_f32_16x16x32_bf16(afr[1], bfr[cg][s], acc[1][cg], 0, 0, 0);
        }
      }
      if (ch == 1) {
        // nga pre-mid epilogue: store bf16, e->LDS, S/V atomics
        float s_acc[4] = {0.f, 0.f, 0.f, 0.f}, v_acc[4] = {0.f, 0.f, 0.f, 0.f};
        int cur_g = indices[row0 + rbase + kg * 4];
#pragma unroll
        for (int rg = 0; rg < 2; ++rg)
#pragma unroll
          for (int r = 0; r < 4; ++r) {
            int m = rbase + rg * 16 + kg * 4 + r;
            int g = indices[row0 + m];
            if (g != cur_g) {
#pragma unroll
              for (int cg = 0; cg < 4; ++cg) {
                atomicAdd(&S_at[cur_g * 64 + cg * 16 + ln15], s_acc[cg]);
                atomicAdd(&V_at[cur_g * 64 + cg * 16 + ln15], v_acc[cg]);
                s_acc[cg] = 0.f; v_acc[cg] = 0.f;
              }
              cur_g = g;
            }
#pragma unroll
            for (int cg = 0; cg < 4; ++cg) {
              float y = acc[rg][cg][r] + bias_c[cg];
              float e = __expf(y);
              s_acc[cg] += e; v_acc[cg] += e * y;
              nga_bf[(size_t)(row0 + m) * 64 + cg * 16 + ln15] = f2bf(y);
              e_lds[m][cg * 16 + ln15] = e;
            }
          }
#pragma unroll
        for (int cg = 0; cg < 4; ++cg) {
          atomicAdd(&S_at[cur_g * 64 + cg * 16 + ln15], s_acc[cg]);
          atomicAdd(&V_at[cur_g * 64 + cg * 16 + ln15], v_acc[cg]);
        }
      }
    } else if (hf == 0) {
      // wave 6: node logits -> exp -> nl_e LDS + Sn atomic
      const float* rp = &buf[lane * 256];
      int lswz = lane & 7;
      float dot = 0.f;
#pragma unroll
      for (int gi = 0; gi < 16; ++gi) {
        f32x4 v = *reinterpret_cast<const f32x4*>(rp + (((gi ^ lswz)) << 2));
        dot += v[0] * w_node[gi * 4 + 0] + v[1] * w_node[gi * 4 + 1]
             + v[2] * w_node[gi * 4 + 2] + v[3] * w_node[gi * 4 + 3];
      }
      float ne = __expf(dot);
      nl_e[lane] = ne;
      atomicAdd(&Sn_at[indices[row0 + lane]], ne);
    } else {
      // wave 7: vsum column segment-sums (lane owns cols lane*4..+3)
      float a0 = 0.f, a1 = 0.f, a2 = 0.f, a3 = 0.f;
      int cur_g = indices[row0];
#pragma unroll 8
      for (int r = 0; r < 64; ++r) {
        int g = indices[row0 + r];
        if (g != cur_g) {
          atomicAdd(&vsum[cur_g * 256 + lane * 4 + 0], a0);
          atomicAdd(&vsum[cur_g * 256 + lane * 4 + 1], a1);
          atomicAdd(&vsum[cur_g * 256 + lane * 4 + 2], a2);
          atomicAdd(&vsum[cur_g * 256 + lane * 4 + 3], a3);
          a0 = a1 = a2 = a3 = 0.f; cur_g = g;
        }
        f32x4 v = *reinterpret_cast<const f32x4*>(&buf[r * 256 + ((lane ^ (r & 7)) << 2)]);
        a0 += v[0]; a1 += v[1]; a2 += v[2]; a3 += v[3];
      }
      atomicAdd(&vsum[cur_g * 256 + lane * 4 + 0], a0);
      atomicAdd(&vsum[cur_g * 256 + lane * 4 + 1], a1);
      atomicAdd(&vsum[cur_g * 256 + lane * 4 + 2], a2);
      atomicAdd(&vsum[cur_g * 256 + lane * 4 + 3], a3);
    }

    asm volatile("s_waitcnt lgkmcnt(0)" ::: "memory");
    __builtin_amdgcn_sched_barrier(0);
    __builtin_amdgcn_s_barrier();          // nl_e / e_lds visible
    __builtin_amdgcn_sched_barrier(0);

    if (is_mfma && ch == 0) {
      // agn post-mid: masked row-softmax -> pa atomics
      float p_acc[4] = {0.f, 0.f, 0.f, 0.f};
      int cur_g = indices[row0 + rbase + kg * 4];
#pragma unroll
      for (int rg = 0; rg < 2; ++rg)
#pragma unroll
        for (int r = 0; r < 4; ++r) {
          int m = rbase + rg * 16 + kg * 4 + r;
          int g = indices[row0 + m];
          if (g != cur_g) {
#pragma unroll
            for (int cg = 0; cg < 4; ++cg) {
              atomicAdd(&pa_un[cur_g * 64 + cg * 16 + ln15], p_acc[cg]);
              p_acc[cg] = 0.f;
            }
            cur_g = g;
          }
          float e[4]; float rsum = 0.f;
#pragma unroll
          for (int cg = 0; cg < 4; ++cg) {
            bool mv = mask_at(mask, kind, g * 64 + cg * 16 + ln15);
            e[cg] = mv ? __expf(acc[rg][cg][r] + bias_c[cg]) : 0.f;
            rsum += e[cg];
          }
          rsum = red16(rsum);
          float ne = nl_e[m];
          if (rsum > 0.f) {
            float inv = ne / rsum;
#pragma unroll
            for (int cg = 0; cg < 4; ++cg) p_acc[cg] += e[cg] * inv;
          } else {
#pragma unroll
            for (int cg = 0; cg < 4; ++cg) p_acc[cg] += ne * 0.015625f;
          }
        }
#pragma unroll
      for (int cg = 0; cg < 4; ++cg)
        atomicAdd(&pa_un[cur_g * 64 + cg * 16 + ln15], p_acc[cg]);
    } else if (is_mfma && ch == 2) {
      // qna post-mid: I = sum e * qna
      float i_acc[4] = {0.f, 0.f, 0.f, 0.f};
      int cur_g = indices[row0 + rbase + kg * 4];
#pragma unroll
      for (int rg = 0; rg < 2; ++rg)
#pragma unroll
        for (int r = 0; r < 4; ++r) {
          int m = rbase + rg * 16 + kg * 4 + r;
          int g = indices[row0 + m];
          if (g != cur_g) {
#pragma unroll
            for (int cg = 0; cg < 4; ++cg) {
              atomicAdd(&I_at[cur_g * 64 + cg * 16 + ln15], i_acc[cg]);
              i_acc[cg] = 0.f;
            }
            cur_g = g;
          }
#pragma unroll
          for (int cg = 0; cg < 4; ++cg)
            i_acc[cg] += e_lds[m][cg * 16 + ln15] * (acc[rg][cg][r] + bias_c[cg]);
        }
#pragma unroll
      for (int cg = 0; cg < 4; ++cg)
        atomicAdd(&I_at[cur_g * 64 + cg * 16 + ln15], i_acc[cg]);
    }
  }
}

// ---------- K2 finalize: per (g,a) -> p_a, Su, entropy, value ----------
__global__ __launch_bounds__(64) void k2_finalize(
    const float* __restrict__ pa_un, const float* __restrict__ S_at,
    const float* __restrict__ V_at, const float* __restrict__ I_at,
    const float* __restrict__ Sn_at, const float* __restrict__ vsum,
    const float* __restrict__ W_qan, const float* __restrict__ b_qan,
    const int* __restrict__ n_nodes, const void* __restrict__ mask,
    const int* __restrict__ mkind,
    float* __restrict__ p_a, float* __restrict__ entropy,
    float* __restrict__ value, float* __restrict__ Su) {
  const int g = blockIdx.x;
  const int a = threadIdx.x;   // 64
  float Sn = Sn_at[g];
  float P = (Sn > 0.f) ? pa_un[g * 64 + a] / Sn : 0.f;
  float S = S_at[g * 64 + a];
  float V = V_at[g * 64 + a];
  float I = I_at[g * 64 + a];
  const float* wv = vsum + g * 256;
  const float* wq = W_qan + (size_t)a * 256;
  float q = 0.f;
#pragma unroll 4
  for (int c = 0; c < 256; c += 4) {
    f32x4 x = *reinterpret_cast<const f32x4*>(wv + c);
    f32x4 y = *reinterpret_cast<const f32x4*>(wq + c);
    q += x[0] * y[0] + x[1] * y[1] + x[2] * y[2] + x[3] * y[3];
  }
  int n = n_nodes[g];
  q += (float)n * b_qan[a];
  bool mva = mask_at(mask, mkind[0], g * 64 + a);
  float Hn;
  if (n <= 0) Hn = 0.f;
  else if (!mva) Hn = -logf(1.0f / (float)n + EPS_V);
  else Hn = (S > 0.f) ? (logf(S) - V / S) : 0.f;
  float inner = (S > 0.f) ? I / S : 0.f;
  float ent = -P * logf(P + EPS_V) + P * Hn;
  float val = P * (q + inner);
  p_a[g * 64 + a] = P;
  Su[g * 64 + a] = S;
  ent = wred_sum(ent);
  val = wred_sum(val);
  if (a == 0) { entropy[g] = ent; value[g] = val; }
}

// ---------- K3: logprob ----------
__global__ __launch_bounds__(256) void k3_logprob(
    const float* __restrict__ p_a, const u16* __restrict__ nga_bf,
    const int* __restrict__ indices, const int* __restrict__ a_action,
    const int* __restrict__ a_node, const void* __restrict__ mask,
    const int* __restrict__ mkind, const int* __restrict__ n_nodes,
    const float* __restrict__ Su, float* __restrict__ logprob, int G) {
  int g = blockIdx.x * blockDim.x + threadIdx.x;
  if (g >= G) return;
  int kind = mkind[0];
  int a = a_action[g];
  float t1 = logf(p_a[g * 64 + a] + EPS_V);
  int node = a_node[g];
  int g2 = indices[node];
  float p2;
  if (mask_at(mask, kind, g2 * 64 + a)) {
    float S = Su[g2 * 64 + a];
    p2 = (S > 0.f) ? __expf(bf2f(nga_bf[(size_t)node * 64 + a])) / S : 0.f;
  } else {
    p2 = 1.0f / (float)n_nodes[g2];
  }
  logprob[g] = t1 + logf(p2 + EPS_V);
}

// ---------- K4: p_n__a = exp(nga)/Su ----------
__global__ __launch_bounds__(256) void k4_pna_bf(
    const u16* __restrict__ nga_bf, const int* __restrict__ indices,
    const float* __restrict__ Su, float* __restrict__ pna, int N) {
  int e8 = blockIdx.x * 256 + threadIdx.x;
  if (e8 >= N * 8) return;
  int i = e8 >> 3, a0 = (e8 & 7) * 8;
  int g = indices[i];
  u16x8 y = *reinterpret_cast<const u16x8*>(nga_bf + (size_t)i * 64 + a0);
  float4 S0 = *reinterpret_cast<const float4*>(Su + g * 64 + a0);
  float4 S1 = *reinterpret_cast<const float4*>(Su + g * 64 + a0 + 4);
  float4 o0, o1;
  o0.x = __expf(bf2f(y[0])) / S0.x; o0.y = __expf(bf2f(y[1])) / S0.y;
  o0.z = __expf(bf2f(y[2])) / S0.z; o0.w = __expf(bf2f(y[3])) / S0.w;
  o1.x = __expf(bf2f(y[4])) / S1.x; o1.y = __expf(bf2f(y[5])) / S1.y;
  o1.z = __expf(bf2f(y[6])) / S1.z; o1.w = __expf(bf2f(y[7])) / S1.w;
  float4* dst = reinterpret_cast<float4*>(pna + (size_t)i * 64 + a0);
  dst[0] = o0; dst[1] = o1;
}

extern "C" void kernel_launch(void* const* d_in, const int* in_sizes, int n_in,
                              void* d_out, int out_size, void* d_ws, size_t ws_size,
                              hipStream_t stream) {
  const float* values = (const float*)d_in[0];
  const int* indices = (const int*)d_in[1];
  const int* a_action = (const int*)d_in[2];
  const int* a_node = (const int*)d_in[3];
  const void* action_mask = d_in[4];
  const int* n_nodes = (const int*)d_in[5];
  const float* w_node = (const float*)d_in[6];
  const float* W_agn = (const float*)d_in[7];
  const float* b_agn = (const float*)d_in[8];
  const float* W_nga = (const float*)d_in[9];
  const float* b_nga = (const float*)d_in[10];
  const float* W_qna = (const float*)d_in[11];
  const float* b_qna = (const float*)d_in[12];
  const float* W_qan = (const float*)d_in[13];
  const float* b_qan = (const float*)d_in[14];

  const int N = in_sizes[1];   // 131072
  const int G = in_sizes[2];   // 256
  const int GA = in_sizes[4];  // G*64

  float* out = (float*)d_out;
  float* o_logprob = out;
  float* o_entropy = out + G;
  float* o_value = out + 2 * G;
  float* o_pa = out + 3 * G;
  float* o_pna = out + 3 * G + GA;

  char* w = (char*)d_ws;
  size_t off = 0;
  u16* nga_bf = (u16*)(w + off); off += (size_t)N * 64 * 2;
  // contiguous zero region: pa_un, S, V, I (GA each), Sn (G), vsum (G*256)
  float* zero_base = (float*)(w + off);
  float* pa_un = (float*)(w + off); off += (size_t)GA * 4;
  float* S_at = (float*)(w + off); off += (size_t)GA * 4;
  float* V_at = (float*)(w + off); off += (size_t)GA * 4;
  float* I_at = (float*)(w + off); off += (size_t)GA * 4;
  float* Sn_at = (float*)(w + off); off += (size_t)G * 4;
  float* vsum = (float*)(w + off); off += (size_t)G * 256 * 4;
  int nzero = 4 * GA + G + G * 256;
  float* Su = (float*)(w + off); off += (size_t)GA * 4;
  int* mkind = (int*)(w + off); off += 256;
  off = (off + 255) & ~(size_t)255;
  u16* Wpack = (u16*)(w + off); off += (size_t)192 * 256 * 2;

  int zero_blocks = (nzero + 255) / 256;
  k0_fused<<<1 + 192 + zero_blocks, 256, 0, stream>>>(
      (const unsigned int*)action_mask, W_agn, W_nga, W_qna,
      mkind, Wpack, zero_base, nzero, GA / 4);
  k1_fused<<<N / (T_TILES * 64), 512, 0, stream>>>(
      values, Wpack, indices, action_mask, mkind,
      b_agn, b_nga, b_qna, w_node,
      nga_bf, pa_un, S_at, V_at, I_at, Sn_at, vsum);
  k2_finalize<<<G, 64, 0, stream>>>(
      pa_un, S_at, V_at, I_at, Sn_at, vsum, W_qan, b_qan,
      n_nodes, action_mask, mkind, o_pa, o_entropy, o_value, Su);
  k3_logprob<<<(G + 255) / 256, 256, 0, stream>>>(
      o_pa, nga_bf, indices, a_action, a_node, action_mask, mkind,
      n_nodes, Su, o_logprob, G);
  k4_pna_bf<<<(N * 8 + 255) / 256, 256, 0, stream>>>(nga_bf, indices, Su, o_pna, N);
}

// Round 8
// 126.266 us; speedup vs baseline: 2.6042x; 2.6042x over previous
//
#include <hip/hip_runtime.h>
#include <hip/hip_bf16.h>

typedef unsigned short u16;
typedef unsigned int u32;
typedef __attribute__((ext_vector_type(4))) float f32x4;
typedef __attribute__((ext_vector_type(8))) short s16x8;
typedef __attribute__((ext_vector_type(8))) unsigned short u16x8;

#define EPS_V (1e-10f)
#define TILES 4                 // 64-row tiles per block
#define NHALF (TILES * 2)       // 32-row halves per block

__device__ __forceinline__ u16 f2bf(float f) {   // RNE (epilogue only)
  unsigned u = __float_as_uint(f);
  u += 0x7fffu + ((u >> 16) & 1u);
  return (u16)(u >> 16);
}
__device__ __forceinline__ float bf2f(u16 h) {
  return __uint_as_float(((unsigned)h) << 16);
}
__device__ __forceinline__ float wred_sum(float v) {
#pragma unroll
  for (int o = 32; o; o >>= 1) v += __shfl_xor(v, o);
  return v;
}
// mask accessor robust to int32 / float32 / byte storage of the bool mask
__device__ __forceinline__ bool mask_at(const void* m, int kind, int idx) {
  if (kind == 0) return ((const int*)m)[idx] != 0;
  if (kind == 1) return ((const float*)m)[idx] != 0.0f;
  return ((const unsigned char*)m)[idx] != 0;
}

// ---------- K0 fused prologue: block 0 = scan, block 1 = mask-detect,
// blocks 2..321 = weight pack, blocks 322.. = zero q_a ----------
__global__ __launch_bounds__(256) void k0_fused(
    const int* __restrict__ n_nodes, const unsigned int* __restrict__ mask_raw,
    const float* __restrict__ w_node, const float* __restrict__ W_agn,
    const float* __restrict__ W_nga, const float* __restrict__ W_qna,
    const float* __restrict__ W_qan,
    int* __restrict__ seg_start, int* __restrict__ mkind,
    float* __restrict__ q_a, u16* __restrict__ Wpack, int G, int ndw) {
  const int b = blockIdx.x;
  const int t = threadIdx.x;
  if (b == 0) {
    if (t < 64) {
      int base = t * 4;
      int v0 = (base + 0 < G) ? n_nodes[base + 0] : 0;
      int v1 = (base + 1 < G) ? n_nodes[base + 1] : 0;
      int v2 = (base + 2 < G) ? n_nodes[base + 2] : 0;
      int v3 = (base + 3 < G) ? n_nodes[base + 3] : 0;
      int lsum = v0 + v1 + v2 + v3;
      int x = lsum;
#pragma unroll
      for (int o = 1; o < 64; o <<= 1) {
        int y = __shfl_up(x, o);
        if (t >= o) x += y;
      }
      int run = x - lsum;  // exclusive prefix
      if (base + 0 < G) seg_start[base + 0] = run; run += v0;
      if (base + 1 < G) seg_start[base + 1] = run; run += v1;
      if (base + 2 < G) seg_start[base + 2] = run; run += v2;
      if (base + 3 < G) seg_start[base + 3] = run; run += v3;
      if (t == 63) seg_start[G] = run;
    }
  } else if (b == 1) {
    __shared__ int notInt, notFloat;
    if (t == 0) { notInt = 0; notFloat = 0; }
    __syncthreads();
    int li = 0, lf = 0;
    for (int i = t; i < ndw; i += 256) {
      unsigned v = mask_raw[i];
      if (v != 0u && v != 1u) li = 1;
      if (v != 0u && v != 0x3F800000u) lf = 1;
    }
    if (li) atomicOr(&notInt, 1);
    if (lf) atomicOr(&notFloat, 1);
    __syncthreads();
    if (t == 0) mkind[0] = (!notInt) ? 0 : ((!notFloat) ? 1 : 2);
  } else if (b < 2 + 320) {
    int idx = (b - 2) * 256 + t;  // < 320*256
    int col = idx >> 8, k = idx & 255;
    float v = 0.f;
    if (col < 64) v = W_agn[col * 256 + k];
    else if (col < 128) v = W_nga[(col - 64) * 256 + k];
    else if (col < 192) v = W_qna[(col - 128) * 256 + k];
    else if (col < 256) v = W_qan[(col - 192) * 256 + k];
    else if (col == 256) v = w_node[k];
    Wpack[idx] = f2bf(v);
  } else {
    int idx = (b - 322) * 256 + t;
    if (idx < G * 64) q_a[idx] = 0.f;
  }
}

// fragment: 8 bf16 of LDS-row m (f32 data), k = k0..k0+7, 16B-granule
// XOR-(m&7) swizzle; truncating convert via v_perm (1 op / 2 elems)
__device__ __forceinline__ s16x8 frag_from_lds(const float* Vf, int m, int k0) {
  int g0 = ((k0 >> 2) ^ (m & 7));      // k0>>2 is even
  int g1 = g0 ^ 1;
  const f32x4 lo = *reinterpret_cast<const f32x4*>(&Vf[m * 256 + g0 * 4]);
  const f32x4 hi = *reinterpret_cast<const f32x4*>(&Vf[m * 256 + g1 * 4]);
  union { s16x8 v; u32 u[4]; } r;
  r.u[0] = __builtin_amdgcn_perm(__float_as_uint(lo[1]), __float_as_uint(lo[0]), 0x07060302u);
  r.u[1] = __builtin_amdgcn_perm(__float_as_uint(lo[3]), __float_as_uint(lo[2]), 0x07060302u);
  r.u[2] = __builtin_amdgcn_perm(__float_as_uint(hi[1]), __float_as_uint(hi[0]), 0x07060302u);
  r.u[3] = __builtin_amdgcn_perm(__float_as_uint(hi[3]), __float_as_uint(hi[2]), 0x07060302u);
  return r.v;
}

// ---------- K1: ring-pipelined GEMM.
// 512 blocks x 256 thr; 8 half-tiles (32 rows) per block through a 4-slot
// 32KB LDS ring fed by global_load_lds. One raw s_barrier per half; counted
// vmcnt(8) (in-order drain => half h+1 landed; h+2 stays in flight).
// Wave w owns col-chunk w (64 cols); B-frags preloaded once (128 VGPR).
// No in-loop atomics: wave 3 run-length-accumulates qan, flushes at end. ----------
__global__ __launch_bounds__(256) void k1_gemm(
    const float* __restrict__ values, const u16* __restrict__ Wpack,
    const int* __restrict__ indices,
    const float* __restrict__ b_agn, const float* __restrict__ b_nga,
    const float* __restrict__ b_qna, const float* __restrict__ b_qan,
    u16* __restrict__ agn, u16* __restrict__ nga_bf, float* __restrict__ nga_f32,
    u16* __restrict__ qna, float* __restrict__ q_a,
    float* __restrict__ nl, int nga_is_bf) {
  __shared__ float ring[4][32 * 256];   // 128 KB, 4 slots of 32 fp32 rows
  const int t = threadIdx.x;
  const int lane = t & 63;
  const int wave = t >> 6;              // = column chunk (0 agn,1 nga,2 qna,3 qan)
  const int ln15 = lane & 15;
  const int kg = lane >> 4;
  const int blk0 = blockIdx.x * (TILES * 64);

  // B fragments for this wave's 64-col chunk, once per block (L2-hot Wpack)
  s16x8 bfr[4][8];
  {
    const u16* wb = Wpack + (size_t)(wave * 64 + ln15) * 256 + kg * 8;
#pragma unroll
    for (int cg = 0; cg < 4; ++cg)
#pragma unroll
      for (int s = 0; s < 8; ++s)
        bfr[cg][s] = *reinterpret_cast<const s16x8*>(wb + (size_t)(cg * 16) * 256 + s * 32);
  }
  float bias_c[4];
  {
    const float* bp = (wave == 0) ? b_agn : (wave == 1) ? b_nga
                    : (wave == 2) ? b_qna : b_qan;
#pragma unroll
    for (int cg = 0; cg < 4; ++cg) bias_c[cg] = bp[cg * 16 + ln15];
  }
  // wave 0 extra: node-logit column (Wpack col 256; 257..271 are zero pad)
  s16x8 bn[8];
  if (wave == 0) {
    const u16* wb = Wpack + (size_t)(256 + ln15) * 256 + kg * 8;
#pragma unroll
    for (int s = 0; s < 8; ++s)
      bn[s] = *reinterpret_cast<const s16x8*>(wb + s * 32);
  }
  // wave 3 qan run-length state (persists across all halves)
  float qpart[4] = {0.f, 0.f, 0.f, 0.f};
  int qg = (wave == 3) ? indices[blk0 + kg * 4] : 0;

#define STAGE(hh)                                                              \
  {                                                                            \
    float* dst_ = ring[(hh) & 3];                                              \
    const int r0_ = blk0 + (hh) * 32;                                          \
    _Pragma("unroll")                                                          \
    for (int i_ = 0; i_ < 8; ++i_) {                                           \
      int m_ = wave * 8 + i_;                                                  \
      const float* gp_ = values + (size_t)(r0_ + m_) * 256 + ((lane ^ (m_ & 7)) << 2); \
      __builtin_amdgcn_global_load_lds(                                        \
          (const __attribute__((address_space(1))) void*)gp_,                  \
          (__attribute__((address_space(3))) void*)&dst_[m_ * 256], 16, 0, 0); \
    }                                                                          \
  }

  STAGE(0);
  STAGE(1);

  for (int h = 0; h < NHALF; ++h) {
    if (h + 2 < NHALF) STAGE(h + 2);
    if (h == NHALF - 1) {
      asm volatile("s_waitcnt vmcnt(0)" ::: "memory");
    } else {
      asm volatile("s_waitcnt vmcnt(8)" ::: "memory");   // newest 8 = h+2 prefetch
    }
    __builtin_amdgcn_sched_barrier(0);
    __builtin_amdgcn_s_barrier();
    __builtin_amdgcn_sched_barrier(0);

    const float* buf = ring[h & 3];
    const int row0 = blk0 + h * 32;

    f32x4 acc[2][4];
#pragma unroll
    for (int mf = 0; mf < 2; ++mf)
#pragma unroll
      for (int cg = 0; cg < 4; ++cg) acc[mf][cg] = (f32x4){0.f, 0.f, 0.f, 0.f};
    f32x4 an0 = (f32x4){0.f, 0.f, 0.f, 0.f};
    f32x4 an1 = (f32x4){0.f, 0.f, 0.f, 0.f};

#pragma unroll
    for (int s = 0; s < 8; ++s) {
      const int k0 = s * 32 + kg * 8;
      s16x8 a0 = frag_from_lds(buf, ln15, k0);
      s16x8 a1 = frag_from_lds(buf, 16 + ln15, k0);
#pragma unroll
      for (int cg = 0; cg < 4; ++cg) {
        acc[0][cg] = __builtin_amdgcn_mfma_f32_16x16x32_bf16(a0, bfr[cg][s], acc[0][cg], 0, 0, 0);
        acc[1][cg] = __builtin_amdgcn_mfma_f32_16x16x32_bf16(a1, bfr[cg][s], acc[1][cg], 0, 0, 0);
      }
      if (wave == 0) {
        an0 = __builtin_amdgcn_mfma_f32_16x16x32_bf16(a0, bn[s], an0, 0, 0, 0);
        an1 = __builtin_amdgcn_mfma_f32_16x16x32_bf16(a1, bn[s], an1, 0, 0, 0);
      }
    }

    // epilogue: C/D map col = lane&15, row = (lane>>4)*4 + reg  [m89/m91]
    if (wave == 3) {
      // qan: run-length accumulate into registers (no atomics in loop)
#pragma unroll
      for (int mf = 0; mf < 2; ++mf)
#pragma unroll
        for (int r = 0; r < 4; ++r) {
          int m = mf * 16 + kg * 4 + r;       // monotone in (mf,r)
          int g = indices[row0 + m];
          if (g != qg) {
#pragma unroll
            for (int cg = 0; cg < 4; ++cg) {
              atomicAdd(&q_a[qg * 64 + cg * 16 + ln15], qpart[cg]);
              qpart[cg] = 0.f;
            }
            qg = g;
          }
#pragma unroll
          for (int cg = 0; cg < 4; ++cg)
            qpart[cg] += acc[mf][cg][r] + bias_c[cg];
        }
    } else {
      u16* dstp = (wave == 0) ? agn : (wave == 1) ? nga_bf : qna;
#pragma unroll
      for (int cg = 0; cg < 4; ++cg) {
        int cl = cg * 16 + ln15;
        float bv = bias_c[cg];
#pragma unroll
        for (int mf = 0; mf < 2; ++mf)
#pragma unroll
          for (int r = 0; r < 4; ++r) {
            int m = mf * 16 + kg * 4 + r;
            float v = acc[mf][cg][r] + bv;
            if (wave == 1 && !nga_is_bf)
              nga_f32[(size_t)(row0 + m) * 64 + cl] = v;
            else
              dstp[(size_t)(row0 + m) * 64 + cl] = f2bf(v);
          }
      }
      if (wave == 0 && ln15 == 0) {
#pragma unroll
        for (int r = 0; r < 4; ++r) {
          nl[row0 + kg * 4 + r] = an0[r];
          nl[row0 + 16 + kg * 4 + r] = an1[r];
        }
      }
    }
  }
#undef STAGE

  if (wave == 3) {
#pragma unroll
    for (int cg = 0; cg < 4; ++cg)
      atomicAdd(&q_a[qg * 64 + cg * 16 + ln15], qpart[cg]);
  }
}

// ---------- K2: one block per segment. No-max softmax (logits bounded ~±2). ----------
__global__ __launch_bounds__(1024) void k2_segment(
    const u16* __restrict__ agn, const u16* __restrict__ nga_bf,
    const float* __restrict__ nga_f32, const u16* __restrict__ qna,
    const float* __restrict__ nl, const int* __restrict__ seg_start,
    const void* __restrict__ mask, const int* __restrict__ mkind,
    const float* __restrict__ q_a,
    float* __restrict__ p_a, float* __restrict__ entropy, float* __restrict__ value,
    float* __restrict__ Su, int nga_is_bf) {
  const int g = blockIdx.x;
  const int s = seg_start[g], e = seg_start[g + 1];
  const int n = e - s;
  const int t = threadIdx.x, lane = t & 63, wave = t >> 6;

  __shared__ float wbuf[16];
  __shared__ float cs[16][64], cv[16][64], ci[16][64], cp[16][64];

  // phase A: Sn = sum exp(nl) over segment
  float ls = 0.f;
  for (int i = s + t; i < e; i += 1024) ls += __expf(nl[i]);
  ls = wred_sum(ls);
  if (lane == 0) wbuf[wave] = ls;
  __syncthreads();
  float Sn = 0.f;
#pragma unroll
  for (int w = 0; w < 16; ++w) Sn += wbuf[w];
  float invSn = (Sn > 0.f) ? 1.f / Sn : 0.f;

  // phase B: wave-per-node stream. lane = action.
  const int kind = mkind[0];
  const bool mv = mask_at(mask, kind, g * 64 + lane);
  float s_u = 0.f, v_u = 0.f, i_u = 0.f, pa = 0.f;
  for (int i = s + wave; i < e; i += 16) {
    size_t base = (size_t)i * 64 + lane;
    float pn = __expf(nl[i]) * invSn;
    float ev = mv ? __expf(bf2f(agn[base])) : 0.f;
    float rs = wred_sum(ev);
    pa += pn * ((rs > 0.f) ? ev / rs : 0.015625f);  // all-masked row -> uniform 1/64
    float y = nga_is_bf ? bf2f(nga_bf[base]) : nga_f32[base];
    float ey = __expf(y);
    s_u += ey;
    v_u += ey * y;
    i_u += ey * bf2f(qna[base]);
  }
  cs[wave][lane] = s_u; cv[wave][lane] = v_u; ci[wave][lane] = i_u;
  cp[wave][lane] = pa;
  __syncthreads();

  if (t < 64) {
    int a = t;
    float S = 0.f, V = 0.f, I = 0.f, P = 0.f;
#pragma unroll
    for (int w = 0; w < 16; ++w) {
      S += cs[w][a]; V += cv[w][a]; I += ci[w][a]; P += cp[w][a];
    }
    p_a[g * 64 + a] = P;
    Su[g * 64 + a] = S;
    float inner = (S > 0.f) ? I / S : 0.f;
    float Q = q_a[g * 64 + a];
    bool mva = mask_at(mask, kind, g * 64 + a);
    float Hn;
    if (n <= 0) Hn = 0.f;
    else if (!mva) Hn = -logf(1.0f / (float)n + EPS_V);   // uniform over segment
    else Hn = (S > 0.f) ? (logf(S) - V / S) : 0.f;
    float ent_c = -P * logf(P + EPS_V) + P * Hn;
    float val_c = P * (Q + inner);
    ent_c = wred_sum(ent_c);
    val_c = wred_sum(val_c);
    if (a == 0) { entropy[g] = ent_c; value[g] = val_c; }
  }
}

// ---------- K3: logprob ----------
__global__ __launch_bounds__(256) void k3_logprob(
    const float* __restrict__ p_a, const u16* __restrict__ nga_bf,
    const float* __restrict__ nga_f32, const int* __restrict__ indices,
    const int* __restrict__ a_action, const int* __restrict__ a_node,
    const void* __restrict__ mask, const int* __restrict__ mkind,
    const int* __restrict__ n_nodes, const float* __restrict__ Su,
    float* __restrict__ logprob, int G, int nga_is_bf) {
  int g = blockIdx.x * blockDim.x + threadIdx.x;
  if (g >= G) return;
  int kind = mkind[0];
  int a = a_action[g];
  float t1 = logf(p_a[g * 64 + a] + EPS_V);
  int node = a_node[g];
  int g2 = indices[node];
  float p2;
  if (mask_at(mask, kind, g2 * 64 + a)) {
    float S = Su[g2 * 64 + a];
    float y = nga_is_bf ? bf2f(nga_bf[(size_t)node * 64 + a]) : nga_f32[(size_t)node * 64 + a];
    p2 = (S > 0.f) ? __expf(y) / S : 0.f;
  } else {
    p2 = 1.0f / (float)n_nodes[g2];
  }
  logprob[g] = t1 + logf(p2 + EPS_V);
}

// ---------- K4 (bf16 path): p_n__a = exp(y)/Su, 8 elems/thread ----------
__global__ __launch_bounds__(256) void k4_pna_bf(
    const u16* __restrict__ nga_bf, const int* __restrict__ indices,
    const float* __restrict__ Su, float* __restrict__ pna, int N) {
  int e8 = blockIdx.x * 256 + threadIdx.x;
  if (e8 >= N * 8) return;
  int i = e8 >> 3, a0 = (e8 & 7) * 8;
  int g = indices[i];
  u16x8 y = *reinterpret_cast<const u16x8*>(nga_bf + (size_t)i * 64 + a0);
  float4 S0 = *reinterpret_cast<const float4*>(Su + g * 64 + a0);
  float4 S1 = *reinterpret_cast<const float4*>(Su + g * 64 + a0 + 4);
  float4 o0, o1;
  o0.x = __expf(bf2f(y[0])) / S0.x; o0.y = __expf(bf2f(y[1])) / S0.y;
  o0.z = __expf(bf2f(y[2])) / S0.z; o0.w = __expf(bf2f(y[3])) / S0.w;
  o1.x = __expf(bf2f(y[4])) / S1.x; o1.y = __expf(bf2f(y[5])) / S1.y;
  o1.z = __expf(bf2f(y[6])) / S1.z; o1.w = __expf(bf2f(y[7])) / S1.w;
  float4* dst = reinterpret_cast<float4*>(pna + (size_t)i * 64 + a0);
  dst[0] = o0; dst[1] = o1;
}

// ---------- K4 (f32 fallback, in-place): p = exp(x)/Su ----------
__global__ __launch_bounds__(256) void k4_pna_f32(
    float* __restrict__ pna, const int* __restrict__ indices,
    const float* __restrict__ Su, int N) {
  int e4 = blockIdx.x * 256 + threadIdx.x;
  if (e4 >= N * 16) return;
  int i = e4 >> 4, a0 = (e4 & 15) * 4;
  int g = indices[i];
  float4* p = reinterpret_cast<float4*>(pna + (size_t)i * 64 + a0);
  float4 x = *p;
  float4 S = *reinterpret_cast<const float4*>(Su + g * 64 + a0);
  float4 o;
  o.x = __expf(x.x) / S.x; o.y = __expf(x.y) / S.y;
  o.z = __expf(x.z) / S.z; o.w = __expf(x.w) / S.w;
  *p = o;
}

extern "C" void kernel_launch(void* const* d_in, const int* in_sizes, int n_in,
                              void* d_out, int out_size, void* d_ws, size_t ws_size,
                              hipStream_t stream) {
  const float* values = (const float*)d_in[0];
  const int* indices = (const int*)d_in[1];
  const int* a_action = (const int*)d_in[2];
  const int* a_node = (const int*)d_in[3];
  const void* action_mask = d_in[4];
  const int* n_nodes = (const int*)d_in[5];
  const float* w_node = (const float*)d_in[6];
  const float* W_agn = (const float*)d_in[7];
  const float* b_agn = (const float*)d_in[8];
  const float* W_nga = (const float*)d_in[9];
  const float* b_nga = (const float*)d_in[10];
  const float* W_qna = (const float*)d_in[11];
  const float* b_qna = (const float*)d_in[12];
  const float* W_qan = (const float*)d_in[13];
  const float* b_qan = (const float*)d_in[14];

  const int N = in_sizes[1];   // 131072
  const int G = in_sizes[2];   // 256
  const int GA = in_sizes[4];  // G*64

  float* out = (float*)d_out;
  float* o_logprob = out;
  float* o_entropy = out + G;
  float* o_value = out + 2 * G;
  float* o_pa = out + 3 * G;
  float* o_pna = out + 3 * G + GA;

  char* w = (char*)d_ws;
  size_t off = 0;
  u16* agn = (u16*)(w + off); off += (size_t)N * 64 * 2;
  u16* qna = (u16*)(w + off); off += (size_t)N * 64 * 2;
  float* nl = (float*)(w + off); off += (size_t)N * 4;
  float* Su = (float*)(w + off); off += (size_t)GA * 4;
  float* q_a = (float*)(w + off); off += (size_t)GA * 4;
  int* seg_start = (int*)(w + off); off += (size_t)(G + 1) * 4;
  int* mkind = (int*)(w + off); off += 256;
  off = (off + 255) & ~(size_t)255;
  u16* Wpack = (u16*)(w + off); off += (size_t)320 * 256 * 2;
  u16* nga_bf = (u16*)(w + off);
  size_t need_bf = off + (size_t)N * 64 * 2;
  int nga_is_bf = (ws_size >= need_bf) ? 1 : 0;
  float* nga_f32 = o_pna;   // fallback: f32 logits staged in d_out, K4 in-place

  int zero_blocks = (GA + 255) / 256;
  k0_fused<<<2 + 320 + zero_blocks, 256, 0, stream>>>(
      n_nodes, (const unsigned int*)action_mask, w_node, W_agn, W_nga, W_qna, W_qan,
      seg_start, mkind, q_a, Wpack, G, GA / 4);
  k1_gemm<<<N / (TILES * 64), 256, 0, stream>>>(
      values, Wpack, indices, b_agn, b_nga, b_qna, b_qan,
      agn, nga_bf, nga_f32, qna, q_a, nl, nga_is_bf);
  k2_segment<<<G, 1024, 0, stream>>>(agn, nga_bf, nga_f32, qna, nl, seg_start,
                                     action_mask, mkind, q_a,
                                     o_pa, o_entropy, o_value, Su, nga_is_bf);
  k3_logprob<<<(G + 255) / 256, 256, 0, stream>>>(
      o_pa, nga_bf, nga_f32, indices, a_action, a_node,
      action_mask, mkind, n_nodes, Su, o_logprob, G, nga_is_bf);
  if (nga_is_bf)
    k4_pna_bf<<<(N * 8 + 255) / 256, 256, 0, stream>>>(nga_bf, indices, Su, o_pna, N);
  else
    k4_pna_f32<<<(N * 16 + 255) / 256, 256, 0, stream>>>(o_pna, indices, Su, N);
}

// Round 9
// 121.159 us; speedup vs baseline: 2.7139x; 1.0422x over previous
//
#include <hip/hip_runtime.h>
#include <hip/hip_bf16.h>

typedef unsigned short u16;
typedef unsigned int u32;
typedef __attribute__((ext_vector_type(4))) float f32x4;
typedef __attribute__((ext_vector_type(8))) short s16x8;
typedef __attribute__((ext_vector_type(8))) unsigned short u16x8;
typedef __attribute__((ext_vector_type(4))) unsigned short u16x4;

#define EPS_V (1e-10f)
#define TILES 4
#define NHALF (TILES * 4)       // 16 halves of 16 rows per block

__device__ __forceinline__ u16 f2bf(float f) {   // RNE
  unsigned u = __float_as_uint(f);
  u += 0x7fffu + ((u >> 16) & 1u);
  return (u16)(u >> 16);
}
__device__ __forceinline__ float bf2f(u16 h) {
  return __uint_as_float(((unsigned)h) << 16);
}
__device__ __forceinline__ float wred_sum(float v) {
#pragma unroll
  for (int o = 32; o; o >>= 1) v += __shfl_xor(v, o);
  return v;
}
__device__ __forceinline__ bool mask_at(const void* m, int kind, int idx) {
  if (kind == 0) return ((const int*)m)[idx] != 0;
  if (kind == 1) return ((const float*)m)[idx] != 0.0f;
  return ((const unsigned char*)m)[idx] != 0;
}

// ---------- K0 fused prologue (unchanged from R8) ----------
__global__ __launch_bounds__(256) void k0_fused(
    const int* __restrict__ n_nodes, const unsigned int* __restrict__ mask_raw,
    const float* __restrict__ w_node, const float* __restrict__ W_agn,
    const float* __restrict__ W_nga, const float* __restrict__ W_qna,
    const float* __restrict__ W_qan,
    int* __restrict__ seg_start, int* __restrict__ mkind,
    float* __restrict__ q_a, u16* __restrict__ Wpack, int G, int ndw) {
  const int b = blockIdx.x;
  const int t = threadIdx.x;
  if (b == 0) {
    if (t < 64) {
      int base = t * 4;
      int v0 = (base + 0 < G) ? n_nodes[base + 0] : 0;
      int v1 = (base + 1 < G) ? n_nodes[base + 1] : 0;
      int v2 = (base + 2 < G) ? n_nodes[base + 2] : 0;
      int v3 = (base + 3 < G) ? n_nodes[base + 3] : 0;
      int lsum = v0 + v1 + v2 + v3;
      int x = lsum;
#pragma unroll
      for (int o = 1; o < 64; o <<= 1) {
        int y = __shfl_up(x, o);
        if (t >= o) x += y;
      }
      int run = x - lsum;
      if (base + 0 < G) seg_start[base + 0] = run; run += v0;
      if (base + 1 < G) seg_start[base + 1] = run; run += v1;
      if (base + 2 < G) seg_start[base + 2] = run; run += v2;
      if (base + 3 < G) seg_start[base + 3] = run; run += v3;
      if (t == 63) seg_start[G] = run;
    }
  } else if (b == 1) {
    __shared__ int notInt, notFloat;
    if (t == 0) { notInt = 0; notFloat = 0; }
    __syncthreads();
    int li = 0, lf = 0;
    for (int i = t; i < ndw; i += 256) {
      unsigned v = mask_raw[i];
      if (v != 0u && v != 1u) li = 1;
      if (v != 0u && v != 0x3F800000u) lf = 1;
    }
    if (li) atomicOr(&notInt, 1);
    if (lf) atomicOr(&notFloat, 1);
    __syncthreads();
    if (t == 0) mkind[0] = (!notInt) ? 0 : ((!notFloat) ? 1 : 2);
  } else if (b < 2 + 320) {
    int idx = (b - 2) * 256 + t;
    int col = idx >> 8, k = idx & 255;
    float v = 0.f;
    if (col < 64) v = W_agn[col * 256 + k];
    else if (col < 128) v = W_nga[(col - 64) * 256 + k];
    else if (col < 192) v = W_qna[(col - 128) * 256 + k];
    else if (col < 256) v = W_qan[(col - 192) * 256 + k];
    else if (col == 256) v = w_node[k];
    Wpack[idx] = f2bf(v);
  } else {
    int idx = (b - 322) * 256 + t;
    if (idx < G * 64) q_a[idx] = 0.f;
  }
}

// fragment: 8 bf16 of LDS-row m (f32 data), k=k0..k0+7, 16B-granule XOR-(m&7)
__device__ __forceinline__ s16x8 frag_from_lds(const float* Vf, int m, int k0) {
  int g0 = ((k0 >> 2) ^ (m & 7));
  int g1 = g0 ^ 1;
  const f32x4 lo = *reinterpret_cast<const f32x4*>(&Vf[m * 256 + g0 * 4]);
  const f32x4 hi = *reinterpret_cast<const f32x4*>(&Vf[m * 256 + g1 * 4]);
  union { s16x8 v; u32 u[4]; } r;
  r.u[0] = __builtin_amdgcn_perm(__float_as_uint(lo[1]), __float_as_uint(lo[0]), 0x07060302u);
  r.u[1] = __builtin_amdgcn_perm(__float_as_uint(lo[3]), __float_as_uint(lo[2]), 0x07060302u);
  r.u[2] = __builtin_amdgcn_perm(__float_as_uint(hi[1]), __float_as_uint(hi[0]), 0x07060302u);
  r.u[3] = __builtin_amdgcn_perm(__float_as_uint(hi[3]), __float_as_uint(hi[2]), 0x07060302u);
  return r.v;
}

// ---------- K1: ring-pipelined GEMM, 16-row halves, coalesced stores.
// 512 blocks x 256 thr (2 blocks/CU: LDS ~72KB). 4-slot x 16KB ring via
// global_load_lds; per-wave exact counted vmcnt (stores included, in-order
// decrement); epilogue transposed through padded LDS -> 4 coalesced b64 stores.
__global__ __launch_bounds__(256) void k1_gemm(
    const float* __restrict__ values, const u16* __restrict__ Wpack,
    const int* __restrict__ indices,
    const float* __restrict__ b_agn, const float* __restrict__ b_nga,
    const float* __restrict__ b_qna, const float* __restrict__ b_qan,
    u16* __restrict__ agn, u16* __restrict__ nga_bf, float* __restrict__ nga_f32,
    u16* __restrict__ qna, float* __restrict__ q_a,
    float* __restrict__ nl, int nga_is_bf) {
  __shared__ float ring[4][16 * 256];   // 64 KB
  __shared__ u16 outbuf[3][16][68];     // pad 68: conflict-free writes, 8B-aligned rows
  __shared__ float nlbuf[16];
  __shared__ int segid[TILES * 64];

  const int t = threadIdx.x;
  const int lane = t & 63;
  const int wave = t >> 6;              // column chunk: 0 agn, 1 nga, 2 qna, 3 qan
  const int ln15 = lane & 15;
  const int kg = lane >> 4;
  const int blk0 = blockIdx.x * (TILES * 64);

  // B fragments for this wave's 64-col chunk (L2-hot), once per block
  s16x8 bfr[4][8];
  {
    const u16* wb = Wpack + (size_t)(wave * 64 + ln15) * 256 + kg * 8;
#pragma unroll
    for (int cg = 0; cg < 4; ++cg)
#pragma unroll
      for (int s = 0; s < 8; ++s)
        bfr[cg][s] = *reinterpret_cast<const s16x8*>(wb + (size_t)(cg * 16) * 256 + s * 32);
  }
  float bias_c[4];
  {
    const float* bp = (wave == 0) ? b_agn : (wave == 1) ? b_nga
                    : (wave == 2) ? b_qna : b_qan;
#pragma unroll
    for (int cg = 0; cg < 4; ++cg) bias_c[cg] = bp[cg * 16 + ln15];
  }
  s16x8 bn[8];
  if (wave == 0) {
    const u16* wb = Wpack + (size_t)(256 + ln15) * 256 + kg * 8;
#pragma unroll
    for (int s = 0; s < 8; ++s)
      bn[s] = *reinterpret_cast<const s16x8*>(wb + s * 32);
  }
  // stage indices to LDS so wave3's epilogue issues no global loads
  if (wave == 3) {
#pragma unroll
    for (int j = 0; j < 4; ++j)
      segid[lane + 64 * j] = indices[blk0 + lane + 64 * j];
  }
  float qpart[4] = {0.f, 0.f, 0.f, 0.f};
  int qg = (wave == 3) ? segid[kg * 4] : 0;

#define STAGE(hh)                                                              \
  {                                                                            \
    float* dst_ = ring[(hh) & 3];                                              \
    const int r0_ = blk0 + (hh) * 16;                                          \
    _Pragma("unroll")                                                          \
    for (int i_ = 0; i_ < 4; ++i_) {                                           \
      int m_ = wave * 4 + i_;                                                  \
      const float* gp_ = values + (size_t)(r0_ + m_) * 256 + ((lane ^ (m_ & 7)) << 2); \
      __builtin_amdgcn_global_load_lds(                                        \
          (const __attribute__((address_space(1))) void*)gp_,                  \
          (__attribute__((address_space(3))) void*)&dst_[m_ * 256], 16, 0, 0); \
    }                                                                          \
  }

  STAGE(0);
  STAGE(1);

  for (int h = 0; h < NHALF; ++h) {
    if (h + 2 < NHALF) STAGE(h + 2);
    // exact counted waits: guarantee loads(h) complete; keep younger ops in flight.
    // steady younger = loads(h+1)[4] + own stores(h-1) + loads(h+2)[4]
    if (!nga_is_bf && wave == 1) {
      asm volatile("s_waitcnt vmcnt(0)" ::: "memory");
    } else if (h == 0) {
      asm volatile("s_waitcnt vmcnt(8)" ::: "memory");
    } else if (h == NHALF - 1) {
      asm volatile("s_waitcnt vmcnt(0)" ::: "memory");
    } else if (h == NHALF - 2) {
      if (wave == 0)      asm volatile("s_waitcnt vmcnt(9)" ::: "memory");
      else if (wave == 3) asm volatile("s_waitcnt vmcnt(4)" ::: "memory");
      else                asm volatile("s_waitcnt vmcnt(8)" ::: "memory");
    } else {
      if (wave == 0)      asm volatile("s_waitcnt vmcnt(13)" ::: "memory");
      else if (wave == 3) asm volatile("s_waitcnt vmcnt(8)" ::: "memory");
      else                asm volatile("s_waitcnt vmcnt(12)" ::: "memory");
    }
    __builtin_amdgcn_sched_barrier(0);
    __builtin_amdgcn_s_barrier();
    __builtin_amdgcn_sched_barrier(0);

    const float* buf = ring[h & 3];
    const int row0 = blk0 + h * 16;

    f32x4 acc[4];
#pragma unroll
    for (int cg = 0; cg < 4; ++cg) acc[cg] = (f32x4){0.f, 0.f, 0.f, 0.f};
    f32x4 an0 = (f32x4){0.f, 0.f, 0.f, 0.f};

#pragma unroll
    for (int s = 0; s < 8; ++s) {
      const int k0 = s * 32 + kg * 8;
      s16x8 a0 = frag_from_lds(buf, ln15, k0);
#pragma unroll
      for (int cg = 0; cg < 4; ++cg)
        acc[cg] = __builtin_amdgcn_mfma_f32_16x16x32_bf16(a0, bfr[cg][s], acc[cg], 0, 0, 0);
      if (wave == 0)
        an0 = __builtin_amdgcn_mfma_f32_16x16x32_bf16(a0, bn[s], an0, 0, 0, 0);
    }

    // epilogue: C/D map col = lane&15, row = (lane>>4)*4 + reg  [m89/m91]
    if (wave == 3) {
      // qan: run-length accumulate (no stores); atomics only at seg boundaries
#pragma unroll
      for (int r = 0; r < 4; ++r) {
        int m = kg * 4 + r;
        int g = segid[h * 16 + m];
        if (g != qg) {
#pragma unroll
          for (int cg = 0; cg < 4; ++cg) {
            atomicAdd(&q_a[qg * 64 + cg * 16 + ln15], qpart[cg]);
            qpart[cg] = 0.f;
          }
          qg = g;
        }
#pragma unroll
        for (int cg = 0; cg < 4; ++cg)
          qpart[cg] += acc[cg][r] + bias_c[cg];
      }
    } else if (wave == 1 && !nga_is_bf) {
      // fallback: scattered f32 stores (drained by vmcnt(0) branch above)
#pragma unroll
      for (int r = 0; r < 4; ++r)
#pragma unroll
        for (int cg = 0; cg < 4; ++cg)
          nga_f32[(size_t)(row0 + kg * 4 + r) * 64 + cg * 16 + ln15] = acc[cg][r] + bias_c[cg];
    } else {
      // transpose through LDS -> coalesced b64 stores (4 instrs, 512B each)
#pragma unroll
      for (int r = 0; r < 4; ++r) {
        int m = kg * 4 + r;
#pragma unroll
        for (int cg = 0; cg < 4; ++cg)
          outbuf[wave][m][cg * 16 + ln15] = f2bf(acc[cg][r] + bias_c[cg]);
      }
      if (wave == 0 && ln15 == 0) {
#pragma unroll
        for (int r = 0; r < 4; ++r) nlbuf[kg * 4 + r] = an0[r];
      }
      u16* dstp = (wave == 0) ? agn : (wave == 1) ? nga_bf : qna;
#pragma unroll
      for (int j = 0; j < 4; ++j) {
        int li = lane + j * 64;
        int rr = li >> 4, cc = (li & 15) * 4;
        u16x4 v = *reinterpret_cast<const u16x4*>(&outbuf[wave][rr][cc]);
        *reinterpret_cast<u16x4*>(dstp + (size_t)row0 * 64 + (size_t)li * 4) = v;
      }
      if (wave == 0 && lane < 16) nl[row0 + lane] = nlbuf[lane];
    }
  }
#undef STAGE

  if (wave == 3) {
#pragma unroll
    for (int cg = 0; cg < 4; ++cg)
      atomicAdd(&q_a[qg * 64 + cg * 16 + ln15], qpart[cg]);
  }
}

// ---------- K2: one block per segment (unchanged) ----------
__global__ __launch_bounds__(1024) void k2_segment(
    const u16* __restrict__ agn, const u16* __restrict__ nga_bf,
    const float* __restrict__ nga_f32, const u16* __restrict__ qna,
    const float* __restrict__ nl, const int* __restrict__ seg_start,
    const void* __restrict__ mask, const int* __restrict__ mkind,
    const float* __restrict__ q_a,
    float* __restrict__ p_a, float* __restrict__ entropy, float* __restrict__ value,
    float* __restrict__ Su, int nga_is_bf) {
  const int g = blockIdx.x;
  const int s = seg_start[g], e = seg_start[g + 1];
  const int n = e - s;
  const int t = threadIdx.x, lane = t & 63, wave = t >> 6;

  __shared__ float wbuf[16];
  __shared__ float cs[16][64], cv[16][64], ci[16][64], cp[16][64];

  float ls = 0.f;
  for (int i = s + t; i < e; i += 1024) ls += __expf(nl[i]);
  ls = wred_sum(ls);
  if (lane == 0) wbuf[wave] = ls;
  __syncthreads();
  float Sn = 0.f;
#pragma unroll
  for (int w = 0; w < 16; ++w) Sn += wbuf[w];
  float invSn = (Sn > 0.f) ? 1.f / Sn : 0.f;

  const int kind = mkind[0];
  const bool mv = mask_at(mask, kind, g * 64 + lane);
  float s_u = 0.f, v_u = 0.f, i_u = 0.f, pa = 0.f;
  for (int i = s + wave; i < e; i += 16) {
    size_t base = (size_t)i * 64 + lane;
    float pn = __expf(nl[i]) * invSn;
    float ev = mv ? __expf(bf2f(agn[base])) : 0.f;
    float rs = wred_sum(ev);
    pa += pn * ((rs > 0.f) ? ev / rs : 0.015625f);
    float y = nga_is_bf ? bf2f(nga_bf[base]) : nga_f32[base];
    float ey = __expf(y);
    s_u += ey;
    v_u += ey * y;
    i_u += ey * bf2f(qna[base]);
  }
  cs[wave][lane] = s_u; cv[wave][lane] = v_u; ci[wave][lane] = i_u;
  cp[wave][lane] = pa;
  __syncthreads();

  if (t < 64) {
    int a = t;
    float S = 0.f, V = 0.f, I = 0.f, P = 0.f;
#pragma unroll
    for (int w = 0; w < 16; ++w) {
      S += cs[w][a]; V += cv[w][a]; I += ci[w][a]; P += cp[w][a];
    }
    p_a[g * 64 + a] = P;
    Su[g * 64 + a] = S;
    float inner = (S > 0.f) ? I / S : 0.f;
    float Q = q_a[g * 64 + a];
    bool mva = mask_at(mask, kind, g * 64 + a);
    float Hn;
    if (n <= 0) Hn = 0.f;
    else if (!mva) Hn = -logf(1.0f / (float)n + EPS_V);
    else Hn = (S > 0.f) ? (logf(S) - V / S) : 0.f;
    float ent_c = -P * logf(P + EPS_V) + P * Hn;
    float val_c = P * (Q + inner);
    ent_c = wred_sum(ent_c);
    val_c = wred_sum(val_c);
    if (a == 0) { entropy[g] = ent_c; value[g] = val_c; }
  }
}

// ---------- K3: logprob (unchanged) ----------
__global__ __launch_bounds__(256) void k3_logprob(
    const float* __restrict__ p_a, const u16* __restrict__ nga_bf,
    const float* __restrict__ nga_f32, const int* __restrict__ indices,
    const int* __restrict__ a_action, const int* __restrict__ a_node,
    const void* __restrict__ mask, const int* __restrict__ mkind,
    const int* __restrict__ n_nodes, const float* __restrict__ Su,
    float* __restrict__ logprob, int G, int nga_is_bf) {
  int g = blockIdx.x * blockDim.x + threadIdx.x;
  if (g >= G) return;
  int kind = mkind[0];
  int a = a_action[g];
  float t1 = logf(p_a[g * 64 + a] + EPS_V);
  int node = a_node[g];
  int g2 = indices[node];
  float p2;
  if (mask_at(mask, kind, g2 * 64 + a)) {
    float S = Su[g2 * 64 + a];
    float y = nga_is_bf ? bf2f(nga_bf[(size_t)node * 64 + a]) : nga_f32[(size_t)node * 64 + a];
    p2 = (S > 0.f) ? __expf(y) / S : 0.f;
  } else {
    p2 = 1.0f / (float)n_nodes[g2];
  }
  logprob[g] = t1 + logf(p2 + EPS_V);
}

// ---------- K4 (bf16): p_n__a = exp(y)/Su ----------
__global__ __launch_bounds__(256) void k4_pna_bf(
    const u16* __restrict__ nga_bf, const int* __restrict__ indices,
    const float* __restrict__ Su, float* __restrict__ pna, int N) {
  int e8 = blockIdx.x * 256 + threadIdx.x;
  if (e8 >= N * 8) return;
  int i = e8 >> 3, a0 = (e8 & 7) * 8;
  int g = indices[i];
  u16x8 y = *reinterpret_cast<const u16x8*>(nga_bf + (size_t)i * 64 + a0);
  float4 S0 = *reinterpret_cast<const float4*>(Su + g * 64 + a0);
  float4 S1 = *reinterpret_cast<const float4*>(Su + g * 64 + a0 + 4);
  float4 o0, o1;
  o0.x = __expf(bf2f(y[0])) / S0.x; o0.y = __expf(bf2f(y[1])) / S0.y;
  o0.z = __expf(bf2f(y[2])) / S0.z; o0.w = __expf(bf2f(y[3])) / S0.w;
  o1.x = __expf(bf2f(y[4])) / S1.x; o1.y = __expf(bf2f(y[5])) / S1.y;
  o1.z = __expf(bf2f(y[6])) / S1.z; o1.w = __expf(bf2f(y[7])) / S1.w;
  float4* dst = reinterpret_cast<float4*>(pna + (size_t)i * 64 + a0);
  dst[0] = o0; dst[1] = o1;
}

// ---------- K4 (f32 fallback, in-place) ----------
__global__ __launch_bounds__(256) void k4_pna_f32(
    float* __restrict__ pna, const int* __restrict__ indices,
    const float* __restrict__ Su, int N) {
  int e4 = blockIdx.x * 256 + threadIdx.x;
  if (e4 >= N * 16) return;
  int i = e4 >> 4, a0 = (e4 & 15) * 4;
  int g = indices[i];
  float4* p = reinterpret_cast<float4*>(pna + (size_t)i * 64 + a0);
  float4 x = *p;
  float4 S = *reinterpret_cast<const float4*>(Su + g * 64 + a0);
  float4 o;
  o.x = __expf(x.x) / S.x; o.y = __expf(x.y) / S.y;
  o.z = __expf(x.z) / S.z; o.w = __expf(x.w) / S.w;
  *p = o;
}

extern "C" void kernel_launch(void* const* d_in, const int* in_sizes, int n_in,
                              void* d_out, int out_size, void* d_ws, size_t ws_size,
                              hipStream_t stream) {
  const float* values = (const float*)d_in[0];
  const int* indices = (const int*)d_in[1];
  const int* a_action = (const int*)d_in[2];
  const int* a_node = (const int*)d_in[3];
  const void* action_mask = d_in[4];
  const int* n_nodes = (const int*)d_in[5];
  const float* w_node = (const float*)d_in[6];
  const float* W_agn = (const float*)d_in[7];
  const float* b_agn = (const float*)d_in[8];
  const float* W_nga = (const float*)d_in[9];
  const float* b_nga = (const float*)d_in[10];
  const float* W_qna = (const float*)d_in[11];
  const float* b_qna = (const float*)d_in[12];
  const float* W_qan = (const float*)d_in[13];
  const float* b_qan = (const float*)d_in[14];

  const int N = in_sizes[1];   // 131072
  const int G = in_sizes[2];   // 256
  const int GA = in_sizes[4];  // G*64

  float* out = (float*)d_out;
  float* o_logprob = out;
  float* o_entropy = out + G;
  float* o_value = out + 2 * G;
  float* o_pa = out + 3 * G;
  float* o_pna = out + 3 * G + GA;

  char* w = (char*)d_ws;
  size_t off = 0;
  u16* agn = (u16*)(w + off); off += (size_t)N * 64 * 2;
  u16* qna = (u16*)(w + off); off += (size_t)N * 64 * 2;
  float* nl = (float*)(w + off); off += (size_t)N * 4;
  float* Su = (float*)(w + off); off += (size_t)GA * 4;
  float* q_a = (float*)(w + off); off += (size_t)GA * 4;
  int* seg_start = (int*)(w + off); off += (size_t)(G + 1) * 4;
  int* mkind = (int*)(w + off); off += 256;
  off = (off + 255) & ~(size_t)255;
  u16* Wpack = (u16*)(w + off); off += (size_t)320 * 256 * 2;
  u16* nga_bf = (u16*)(w + off);
  size_t need_bf = off + (size_t)N * 64 * 2;
  int nga_is_bf = (ws_size >= need_bf) ? 1 : 0;
  float* nga_f32 = o_pna;

  int zero_blocks = (GA + 255) / 256;
  k0_fused<<<2 + 320 + zero_blocks, 256, 0, stream>>>(
      n_nodes, (const unsigned int*)action_mask, w_node, W_agn, W_nga, W_qna, W_qan,
      seg_start, mkind, q_a, Wpack, G, GA / 4);
  k1_gemm<<<N / (TILES * 64), 256, 0, stream>>>(
      values, Wpack, indices, b_agn, b_nga, b_qna, b_qan,
      agn, nga_bf, nga_f32, qna, q_a, nl, nga_is_bf);
  k2_segment<<<G, 1024, 0, stream>>>(agn, nga_bf, nga_f32, qna, nl, seg_start,
                                     action_mask, mkind, q_a,
                                     o_pa, o_entropy, o_value, Su, nga_is_bf);
  k3_logprob<<<(G + 255) / 256, 256, 0, stream>>>(
      o_pa, nga_bf, nga_f32, indices, a_action, a_node,
      action_mask, mkind, n_nodes, Su, o_logprob, G, nga_is_bf);
  if (nga_is_bf)
    k4_pna_bf<<<(N * 8 + 255) / 256, 256, 0, stream>>>(nga_bf, indices, Su, o_pna, N);
  else
    k4_pna_f32<<<(N * 16 + 255) / 256, 256, 0, stream>>>(o_pna, indices, Su, N);
}